// Round 12
// baseline (248.249 us; speedup 1.0000x reference)
//
#include <hip/hip_runtime.h>
#include <cstdint>

#define WIDTH 128
#define NCOMBO 2268   // 6*7*3*18 attr-combo rows
#define XSL 136       // bf16 LDS tile row stride (128 + 8 pad)
#define OSL 132       // f32 LDS tile row stride (128 + 4 pad)
#define TOTW (6 * 16384)
#define TOTU (3 * 34 * WIDTH)

typedef short bf16x8 __attribute__((ext_vector_type(8)));
typedef float f32x4  __attribute__((ext_vector_type(4)));
typedef float f32x2  __attribute__((ext_vector_type(2)));

// gelu(v) = v * sigmoid(2u): ~9 VALU ops, inf-safe.
__device__ __forceinline__ float gelu_fast(float v) {
    float e = __expf(v * __builtin_fmaf(v * v, 0.0713548f, 1.5957691f));
    return v - v * __builtin_amdgcn_rcpf(e + 1.0f);
}
// packed-pair gelu: vector ops pack to v_pk_*; exp/rcp stay scalar (no pk form).
__device__ __forceinline__ f32x2 gelu2(f32x2 v) {
    f32x2 u = v * (v * v * 0.0713548f + 1.5957691f);
    f32x2 r;
    r.x = __builtin_amdgcn_rcpf(__expf(u.x) + 1.0f);
    r.y = __builtin_amdgcn_rcpf(__expf(u.y) + 1.0f);
    return v - v * r;
}
__device__ __forceinline__ short f2b(float f) {
    unsigned u = __float_as_uint(f);
    unsigned r = (u + 0x7FFFu + ((u >> 16) & 1u)) >> 16;
    return (short)r;
}
__device__ __forceinline__ float b2f_lo(unsigned u) { return __uint_as_float(u << 16); }
__device__ __forceinline__ float b2f_hi(unsigned u) { return __uint_as_float(u & 0xFFFF0000u); }
__device__ __forceinline__ unsigned pack2(float lo, float hi) {
    return (unsigned)(unsigned short)f2b(lo) | ((unsigned)(unsigned short)f2b(hi) << 16);
}

// ---------------------------------------------------------------------------
// F1: (a) 6 weight mats -> bf16 fragment-order tables; (b) U tables;
// (c) scal; (d) hist with rank (counts pre-zeroed by memset).
// ---------------------------------------------------------------------------
__global__ void k_f1(const float* __restrict__ einit, const float* __restrict__ init0,
                     const float* __restrict__ emb0, const float* __restrict__ emb1,
                     const float* __restrict__ emb2, const float* __restrict__ emb3,
                     const float* __restrict__ r0w, const float* __restrict__ r0b,
                     const float* __restrict__ r1w, const float* __restrict__ r1b,
                     const float* __restrict__ r2w, const float* __restrict__ r2b,
                     const float* __restrict__ pw0, const float* __restrict__ pw1,
                     const float* __restrict__ pw2, const float* __restrict__ pw3,
                     const float* __restrict__ pw4, const float* __restrict__ pw5,
                     short* __restrict__ o0, short* __restrict__ o1,
                     short* __restrict__ o2, short* __restrict__ o3,
                     short* __restrict__ o4, short* __restrict__ o5,
                     float* __restrict__ U, float* __restrict__ scal,
                     const int* __restrict__ edge_index, int* __restrict__ counts,
                     int* __restrict__ rank, int E) {
    int tid = blockIdx.x * blockDim.x + threadIdx.x;
    if (tid == 0) { scal[0] = init0[0]; scal[1] = init0[1]; }
    if (tid < TOTW) {
        int which = tid >> 14;
        int r = tid & 16383;
        int t    = r >> 11;
        int kc   = (r >> 9) & 3;
        int lane = (r >> 3) & 63;
        int j    = r & 7;
        int k  = kc * 32 + ((lane >> 4) << 3) + j;
        int nn = (t << 4) + (lane & 15);
        const float* w = (which == 0) ? pw0 : (which == 1) ? pw1 : (which == 2) ? pw2
                       : (which == 3) ? pw3 : (which == 4) ? pw4 : pw5;
        short* o = (which == 0) ? o0 : (which == 1) ? o1 : (which == 2) ? o2
                 : (which == 3) ? o3 : (which == 4) ? o4 : o5;
        o[r] = f2b(w[k * 128 + nn]);
    } else if (tid < TOTW + TOTU) {
        int idx = tid - TOTW;
        float e0 = expf(einit[0]), e1 = expf(einit[1]), e2 = expf(einit[2]), e3 = expf(einit[3]);
        float inv = 1.0f / sqrtf(e0 + e1 + e2 + e3);
        float xw[4] = {e0 * inv, e1 * inv, e2 * inv, e3 * inv};
        float se = expf(init0[2]);
        float sv = expf(init0[3]);
        int r   = idx / (34 * WIDTH);
        int rem = idx - r * (34 * WIDTH);
        int g   = rem / WIDTH;
        int j   = rem - g * WIDTH;
        int cc, base;
        if (g >= 16)      { cc = 3; base = 16; }
        else if (g >= 13) { cc = 2; base = 13; }
        else if (g >= 6)  { cc = 1; base = 6; }
        else              { cc = 0; base = 0; }
        int i = g - base;
        const float* em = (cc == 0) ? emb0 : (cc == 1) ? emb1 : (cc == 2) ? emb2 : emb3;
        const float* w  = (r == 0) ? r0w : (r == 1) ? r1w : r2w;
        const float* rb = (r == 0) ? r0b : (r == 1) ? r1b : r2b;
        float s = (r == 2) ? sv : se;
        float acc = 0.0f;
        const float* erow = em + i * 64;
        for (int d = 0; d < 64; ++d) acc += erow[d] * w[d * WIDTH + j];
        float val = s * xw[cc] * acc;
        if (cc == 0) val += s * rb[j];
        U[idx] = val;
    } else if (tid < TOTW + TOTU + E) {
        int e = tid - TOTW - TOTU;
        rank[e] = atomicAdd(&counts[edge_index[E + e]], 1);
    }
}

// ---------------------------------------------------------------------------
// F2: blocks [0,sb): scan1; last scan1 block to finish also performs scan2
// (exclusive scan of partials + grand total) — no separate launch.
//     blocks [sb,...): prepc (2 combo-rows per block; fast path skips r<2).
// ---------------------------------------------------------------------------
__global__ void k_f2(const int* __restrict__ counts, int* __restrict__ lscan,
                     int* __restrict__ partials, int* __restrict__ done,
                     int* __restrict__ offsets, int n, int sb,
                     const float* __restrict__ U, const float* __restrict__ init0,
                     float* __restrict__ Uc) {
    if ((int)blockIdx.x < sb) {
        __shared__ int s[256];
        __shared__ int lastFlag;
        int t = threadIdx.x;
        int i = blockIdx.x * 256 + t;
        int v = (i < n) ? counts[i] : 0;
        s[t] = v;
        __syncthreads();
        for (int d = 1; d < 256; d <<= 1) {
            int u = (t >= d) ? s[t - d] : 0;
            __syncthreads();
            s[t] += u;
            __syncthreads();
        }
        if (i < n) lscan[i] = s[t];
        if (t == 255) partials[blockIdx.x] = s[255];
        // last-block-done: the final finisher scans the partials (sb <= 256).
        __threadfence();
        if (t == 0) {
            int prev = atomicAdd(done, 1);
            lastFlag = (prev == sb - 1) ? 1 : 0;
        }
        __syncthreads();
        if (lastFlag) {
            int v2 = (t < sb) ? partials[t] : 0;
            s[t] = v2;
            __syncthreads();
            for (int d = 1; d < 256; d <<= 1) {
                int u = (t >= d) ? s[t - d] : 0;
                __syncthreads();
                s[t] += u;
                __syncthreads();
            }
            if (t < sb) partials[t] = s[t] - v2;   // exclusive prefix
            if (t == 255) offsets[n] = s[255];     // grand total
        }
    } else {
        int bi = ((int)blockIdx.x - sb) * 2 + (threadIdx.x >> 7);
        if (bi >= 3 * NCOMBO) return;
        int r  = bi / NCOMBO;
        if (r < 2 && init0[0] == 0.0f) return;
        int cb = bi - r * NCOMBO;
        int a  = cb / 378;
        int rm = cb - a * 378;
        int b  = rm / 54;
        rm -= b * 54;
        int c  = rm / 18;
        int d  = rm - c * 18;
        int j  = threadIdx.x & 127;
        const float* Ur = U + r * 34 * WIDTH;
        Uc[(size_t)bi * WIDTH + j] = Ur[a * WIDTH + j] + Ur[(6 + b) * WIDTH + j]
                                   + Ur[(13 + c) * WIDTH + j] + Ur[(16 + d) * WIDTH + j];
    }
}

// ---------------------------------------------------------------------------
// F3: blocks [0,gb): gemm12.  [gb,gb+eb): scatter (uint2{src*64, combo*64}).
//     [gb+eb,...): scan3 (offsets[] for k_agg).
// ---------------------------------------------------------------------------
__global__ void __launch_bounds__(256, 2) k_f3(
        const float* __restrict__ x,
        const short* __restrict__ preF, const float* __restrict__ pre_b,
        const short* __restrict__ w0F, const float* __restrict__ b0,
        const short* __restrict__ w1F, const float* __restrict__ b1,
        const short* __restrict__ w2F, const float* __restrict__ b2,
        const short* __restrict__ w3F, const float* __restrict__ b3,
        const float* __restrict__ scal,
        short* __restrict__ Gb, float* __restrict__ A,
        short* __restrict__ Bb, short* __restrict__ Cb, int n,
        const int* __restrict__ edge_index, const int* __restrict__ edge_attr,
        const int* __restrict__ counts, const int* __restrict__ lscan,
        const int* __restrict__ partials, const int* __restrict__ rank,
        int* __restrict__ offsets, uint2* __restrict__ s_pk, int E,
        int gb, int eb) {
    __shared__ short xs_raw[64 * XSL];
    __shared__ short xs_xx[64 * XSL];
    int tid = threadIdx.x;

    if ((int)blockIdx.x >= gb) {
        int rb = (int)blockIdx.x - gb;
        if (rb < eb) {
            int e = rb * 256 + tid;
            if (e >= E) return;
            int src = edge_index[e];
            int dst = edge_index[E + e];
            int4 at = ((const int4*)edge_attr)[e];
            int combo = ((at.x * 7 + at.y) * 3 + at.z) * 18 + at.w;
            int off = partials[dst >> 8] + lscan[dst] - counts[dst];
            uint2 pk;
            pk.x = (unsigned)src * 64u;
            pk.y = (unsigned)combo * 64u;
            s_pk[off + rank[e]] = pk;
        } else {
            int i = (rb - eb) * 256 + tid;
            if (i >= n) return;
            offsets[i] = partials[i >> 8] + lscan[i] - counts[i];
        }
        return;
    }

    // ---- gemm12 ----
    int w    = tid >> 6;
    int lane = tid & 63;
    int quad = lane >> 4, l16 = lane & 15;
    int m0   = blockIdx.x * 64;

    bf16x8 Bg[2][4], Bc[2][4];
#pragma unroll
    for (int tt = 0; tt < 2; ++tt)
#pragma unroll
        for (int kc = 0; kc < 4; ++kc) {
            int fo = (((2 * w + tt) * 4 + kc) * 64 + lane) * 8;
            Bg[tt][kc] = *(const bf16x8*)(w0F + fo);
            Bc[tt][kc] = *(const bf16x8*)(w3F + fo);
        }

#pragma unroll
    for (int it = 0; it < 8; ++it) {
        int fi  = it * 256 + tid;
        int row = fi >> 5, c4 = fi & 31;
        int gr  = min(m0 + row, n - 1);
        float4 v = ((const float4*)x)[(size_t)gr * 32 + c4];
        uint2 p;
        p.x = pack2(v.x, v.y);
        p.y = pack2(v.z, v.w);
        *(uint2*)(&xs_raw[row * XSL + c4 * 4]) = p;
    }
    __syncthreads();

    {
        bf16x8 a[4];
#pragma unroll
        for (int kc = 0; kc < 4; ++kc)
            a[kc] = *(const bf16x8*)(&xs_raw[(w * 16 + l16) * XSL + kc * 32 + quad * 8]);
        f32x4 acc[8];
#pragma unroll
        for (int t = 0; t < 8; ++t) acc[t] = (f32x4){0.f, 0.f, 0.f, 0.f};
#pragma unroll
        for (int kc = 0; kc < 4; ++kc)
#pragma unroll
            for (int t = 0; t < 8; ++t) {
                bf16x8 b = *(const bf16x8*)(preF + ((t * 4 + kc) * 64 + lane) * 8);
                acc[t] = __builtin_amdgcn_mfma_f32_16x16x32_bf16(a[kc], b, acc[t], 0, 0, 0);
            }
#pragma unroll
        for (int t = 0; t < 8; ++t) {
            float bv = pre_b[t * 16 + l16];
#pragma unroll
            for (int r = 0; r < 4; ++r) acc[t][r] += bv;
        }
#pragma unroll
        for (int r = 0; r < 4; ++r) {
            float s = 0.f, s2 = 0.f;
#pragma unroll
            for (int t = 0; t < 8; ++t) { float v = acc[t][r]; s += v; s2 += v * v; }
            s  += __shfl_xor(s, 1);  s2 += __shfl_xor(s2, 1);
            s  += __shfl_xor(s, 2);  s2 += __shfl_xor(s2, 2);
            s  += __shfl_xor(s, 4);  s2 += __shfl_xor(s2, 4);
            s  += __shfl_xor(s, 8);  s2 += __shfl_xor(s2, 8);
            float m   = s * (1.0f / WIDTH);
            float var = s2 * (1.0f / WIDTH) - m * m;
            float rs  = rsqrtf(var + 1e-5f);
#pragma unroll
            for (int t = 0; t < 8; ++t) acc[t][r] = (acc[t][r] - m) * rs;
        }
        int rowb = w * 16 + quad * 4;
#pragma unroll
        for (int t = 0; t < 8; ++t)
#pragma unroll
            for (int r = 0; r < 4; ++r)
                xs_xx[(rowb + r) * XSL + t * 16 + l16] = f2b(acc[t][r]);
    }
    __syncthreads();

    bf16x8 a2[4][4];
#pragma unroll
    for (int i = 0; i < 4; ++i)
#pragma unroll
        for (int kc = 0; kc < 4; ++kc)
            a2[i][kc] = *(const bf16x8*)(&xs_xx[(i * 16 + l16) * XSL + kc * 32 + quad * 8]);
    __syncthreads();

    {
        f32x4 accG[4][2], accC[4][2];
#pragma unroll
        for (int i = 0; i < 4; ++i)
#pragma unroll
            for (int tt = 0; tt < 2; ++tt) {
                accG[i][tt] = (f32x4){0.f,0.f,0.f,0.f};
                accC[i][tt] = (f32x4){0.f,0.f,0.f,0.f};
            }
#pragma unroll
        for (int kc = 0; kc < 4; ++kc)
#pragma unroll
            for (int i = 0; i < 4; ++i)
#pragma unroll
                for (int tt = 0; tt < 2; ++tt) {
                    accG[i][tt] = __builtin_amdgcn_mfma_f32_16x16x32_bf16(a2[i][kc], Bg[tt][kc], accG[i][tt], 0, 0, 0);
                    accC[i][tt] = __builtin_amdgcn_mfma_f32_16x16x32_bf16(a2[i][kc], Bc[tt][kc], accC[i][tt], 0, 0, 0);
                }
#pragma unroll
        for (int tt = 0; tt < 2; ++tt) {
            int col = (2 * w + tt) * 16 + l16;
            float bg = b0[col];
            float bc = b3[col];
#pragma unroll
            for (int i = 0; i < 4; ++i)
#pragma unroll
                for (int r = 0; r < 4; ++r) {
                    int row = i * 16 + quad * 4 + r;
                    xs_raw[row * XSL + col] = f2b(gelu_fast(accG[i][tt][r] + bg));
                    xs_xx[row * XSL + col]  = f2b(accC[i][tt][r] + bc);
                }
        }
    }
    __syncthreads();

#pragma unroll
    for (int it = 0; it < 4; ++it) {
        int si  = it * 256 + tid;
        int row = si >> 4, c8 = si & 15;
        if (m0 + row < n) {
            *(bf16x8*)(Gb + (size_t)(m0 + row) * WIDTH + c8 * 8) = *(const bf16x8*)(&xs_raw[row * XSL + c8 * 8]);
            *(bf16x8*)(Cb + (size_t)(m0 + row) * WIDTH + c8 * 8) = *(const bf16x8*)(&xs_xx[row * XSL + c8 * 8]);
        }
    }

    if (scal[0] != 0.0f) {
        bf16x8 Ba[2][4], Bbf[2][4];
#pragma unroll
        for (int tt = 0; tt < 2; ++tt)
#pragma unroll
            for (int kc = 0; kc < 4; ++kc) {
                int fo = (((2 * w + tt) * 4 + kc) * 64 + lane) * 8;
                Ba[tt][kc]  = *(const bf16x8*)(w1F + fo);
                Bbf[tt][kc] = *(const bf16x8*)(w2F + fo);
            }
        f32x4 accA[4][2], accB[4][2];
#pragma unroll
        for (int i = 0; i < 4; ++i)
#pragma unroll
            for (int tt = 0; tt < 2; ++tt) {
                accA[i][tt] = (f32x4){0.f,0.f,0.f,0.f};
                accB[i][tt] = (f32x4){0.f,0.f,0.f,0.f};
            }
#pragma unroll
        for (int kc = 0; kc < 4; ++kc)
#pragma unroll
            for (int i = 0; i < 4; ++i)
#pragma unroll
                for (int tt = 0; tt < 2; ++tt) {
                    accA[i][tt] = __builtin_amdgcn_mfma_f32_16x16x32_bf16(a2[i][kc], Ba[tt][kc],  accA[i][tt], 0, 0, 0);
                    accB[i][tt] = __builtin_amdgcn_mfma_f32_16x16x32_bf16(a2[i][kc], Bbf[tt][kc], accB[i][tt], 0, 0, 0);
                }
#pragma unroll
        for (int tt = 0; tt < 2; ++tt) {
            int col = (2 * w + tt) * 16 + l16;
            float ba = b1[col];
            float bb = b2[col];
#pragma unroll
            for (int i = 0; i < 4; ++i)
#pragma unroll
                for (int r = 0; r < 4; ++r) {
                    int row = m0 + i * 16 + quad * 4 + r;
                    if (row < n) {
                        size_t idx = (size_t)row * WIDTH + col;
                        A[idx]  = accA[i][tt][r] + ba;
                        Bb[idx] = f2b(accB[i][tt][r] + bb);
                    }
                }
        }
    }
}

// ---------------------------------------------------------------------------
// k_agg v4: one wave per node, lane L owns cols {2L,2L+1}. Pre-scaled uint2
// edge stream (indices = src*64, combo*64) + packed f32x2 math (v_pk_*).
// Fast path unrolled x4 with hoisted loads.
// ---------------------------------------------------------------------------
__global__ void __launch_bounds__(256)
k_agg(const int* __restrict__ offsets, const uint2* __restrict__ s_pk,
      const float* __restrict__ A, const short* __restrict__ Bb,
      const short* __restrict__ Cb, const float* __restrict__ Uc,
      const float* __restrict__ scal, const short* __restrict__ Gb,
      short* __restrict__ hb, int n) {
    int wid = threadIdx.x >> 6;
    int L   = threadIdx.x & 63;
    int node = blockIdx.x * 4 + wid;
    if (node >= n) return;
    int start = offsets[node];
    int end   = offsets[node + 1];

    const unsigned* Cb32 = (const unsigned*)Cb;
    const unsigned* Bb32 = (const unsigned*)Bb;
    const f32x2* U0c2 = (const f32x2*)(Uc);
    const f32x2* U1c2 = (const f32x2*)(Uc + (size_t)NCOMBO * WIDTH);
    const f32x2* U2c2 = (const f32x2*)(Uc + 2 * (size_t)NCOMBO * WIDTH);

    float i0 = scal[0], i1 = scal[1];
    f32x2 acc = (f32x2){0.f, 0.f};

    if (i0 == 0.0f) {
        int p = start;
        for (; p + 4 <= end; p += 4) {
            uint2 pk0 = s_pk[p],     pk1 = s_pk[p + 1];
            uint2 pk2 = s_pk[p + 2], pk3 = s_pk[p + 3];
            unsigned cc0 = Cb32[pk0.x + L];
            unsigned cc1 = Cb32[pk1.x + L];
            unsigned cc2 = Cb32[pk2.x + L];
            unsigned cc3 = Cb32[pk3.x + L];
            f32x2 uu0 = U2c2[pk0.y + L];
            f32x2 uu1 = U2c2[pk1.y + L];
            f32x2 uu2 = U2c2[pk2.y + L];
            f32x2 uu3 = U2c2[pk3.y + L];
            acc += gelu2((f32x2){b2f_lo(cc0), b2f_hi(cc0)} + uu0);
            acc += gelu2((f32x2){b2f_lo(cc1), b2f_hi(cc1)} + uu1);
            acc += gelu2((f32x2){b2f_lo(cc2), b2f_hi(cc2)} + uu2);
            acc += gelu2((f32x2){b2f_lo(cc3), b2f_hi(cc3)} + uu3);
        }
        if (p + 2 <= end) {
            uint2 pk0 = s_pk[p], pk1 = s_pk[p + 1];
            unsigned cc0 = Cb32[pk0.x + L];
            unsigned cc1 = Cb32[pk1.x + L];
            f32x2 uu0 = U2c2[pk0.y + L];
            f32x2 uu1 = U2c2[pk1.y + L];
            acc += gelu2((f32x2){b2f_lo(cc0), b2f_hi(cc0)} + uu0);
            acc += gelu2((f32x2){b2f_lo(cc1), b2f_hi(cc1)} + uu1);
            p += 2;
        }
        if (p < end) {
            uint2 pk0 = s_pk[p];
            unsigned cc0 = Cb32[pk0.x + L];
            f32x2 uu0 = U2c2[pk0.y + L];
            acc += gelu2((f32x2){b2f_lo(cc0), b2f_hi(cc0)} + uu0);
        }
        acc *= __expf(i1);
    } else {
        f32x2 av = *(const f32x2*)(A + (size_t)node * WIDTH + 2 * L);
        int p = start;
        for (; p + 2 <= end; p += 2) {
            uint2 pk0 = s_pk[p], pk1 = s_pk[p + 1];
            f32x2 u0a = U0c2[pk0.y + L], u0b = U0c2[pk1.y + L];
            f32x2 u1a = U1c2[pk0.y + L], u1b = U1c2[pk1.y + L];
            f32x2 u2a = U2c2[pk0.y + L], u2b = U2c2[pk1.y + L];
            unsigned bba = Bb32[pk0.x + L], bbb = Bb32[pk1.x + L];
            unsigned cca = Cb32[pk0.x + L], ccb = Cb32[pk1.x + L];
            {
                f32x2 q = av + u0a;
                f32x2 k = (f32x2){b2f_lo(bba), b2f_hi(bba)} + u1a;
                f32x2 v = gelu2((f32x2){b2f_lo(cca), b2f_hi(cca)} + u2a);
                float s = q.x * k.x + q.y * k.y;
                s += __shfl_xor(s, 1);
                s += __shfl_xor(s, 2);
                s += __shfl_xor(s, 4);
                s += __shfl_xor(s, 8);
                s += __shfl_xor(s, 16);
                acc += v * __expf(s * 0.125f * i0 + i1);
            }
            {
                f32x2 q = av + u0b;
                f32x2 k = (f32x2){b2f_lo(bbb), b2f_hi(bbb)} + u1b;
                f32x2 v = gelu2((f32x2){b2f_lo(ccb), b2f_hi(ccb)} + u2b);
                float s = q.x * k.x + q.y * k.y;
                s += __shfl_xor(s, 1);
                s += __shfl_xor(s, 2);
                s += __shfl_xor(s, 4);
                s += __shfl_xor(s, 8);
                s += __shfl_xor(s, 16);
                acc += v * __expf(s * 0.125f * i0 + i1);
            }
        }
        if (p < end) {
            uint2 pk = s_pk[p];
            f32x2 u0 = U0c2[pk.y + L];
            f32x2 u1 = U1c2[pk.y + L];
            f32x2 u2 = U2c2[pk.y + L];
            unsigned bb = Bb32[pk.x + L];
            unsigned cc = Cb32[pk.x + L];
            f32x2 q = av + u0;
            f32x2 k = (f32x2){b2f_lo(bb), b2f_hi(bb)} + u1;
            f32x2 v = gelu2((f32x2){b2f_lo(cc), b2f_hi(cc)} + u2);
            float s = q.x * k.x + q.y * k.y;
            s += __shfl_xor(s, 1);
            s += __shfl_xor(s, 2);
            s += __shfl_xor(s, 4);
            s += __shfl_xor(s, 8);
            s += __shfl_xor(s, 16);
            acc += v * __expf(s * 0.125f * i0 + i1);
        }
    }
    unsigned g = ((const unsigned*)Gb)[(size_t)node * 64 + L];
    ((unsigned*)hb)[(size_t)node * 64 + L] = pack2(b2f_lo(g) + acc.x, b2f_hi(g) + acc.y);
}

// ---------------------------------------------------------------------------
// k_post: coop-load hb -> LDS, B-stationary MFMA, staged coalesced out.
// ---------------------------------------------------------------------------
__global__ void __launch_bounds__(256, 2) k_post(
        const float* __restrict__ x, const short* __restrict__ hb,
        const short* __restrict__ postF, const float* __restrict__ post_b,
        float* __restrict__ out, int n) {
    __shared__ short hs[64 * XSL];
    __shared__ float os[64 * OSL];
    int tid  = threadIdx.x;
    int w    = tid >> 6;
    int lane = tid & 63;
    int quad = lane >> 4, l16 = lane & 15;
    int m0   = blockIdx.x * 64;

    bf16x8 Bp[2][4];
#pragma unroll
    for (int tt = 0; tt < 2; ++tt)
#pragma unroll
        for (int kc = 0; kc < 4; ++kc)
            Bp[tt][kc] = *(const bf16x8*)(postF + (((2 * w + tt) * 4 + kc) * 64 + lane) * 8);

#pragma unroll
    for (int it = 0; it < 4; ++it) {
        int si  = it * 256 + tid;
        int row = si >> 4, c8 = si & 15;
        int gr  = min(m0 + row, n - 1);
        *(bf16x8*)(&hs[row * XSL + c8 * 8]) = *(const bf16x8*)(hb + (size_t)gr * WIDTH + c8 * 8);
    }
    __syncthreads();

    bf16x8 a[4][4];
#pragma unroll
    for (int i = 0; i < 4; ++i)
#pragma unroll
        for (int kc = 0; kc < 4; ++kc)
            a[i][kc] = *(const bf16x8*)(&hs[(i * 16 + l16) * XSL + kc * 32 + quad * 8]);

    f32x4 acc[4][2];
#pragma unroll
    for (int i = 0; i < 4; ++i)
#pragma unroll
        for (int tt = 0; tt < 2; ++tt) acc[i][tt] = (f32x4){0.f,0.f,0.f,0.f};
#pragma unroll
    for (int kc = 0; kc < 4; ++kc)
#pragma unroll
        for (int i = 0; i < 4; ++i)
#pragma unroll
            for (int tt = 0; tt < 2; ++tt)
                acc[i][tt] = __builtin_amdgcn_mfma_f32_16x16x32_bf16(a[i][kc], Bp[tt][kc], acc[i][tt], 0, 0, 0);

#pragma unroll
    for (int tt = 0; tt < 2; ++tt) {
        int col = (2 * w + tt) * 16 + l16;
        float bv = post_b[col];
#pragma unroll
        for (int i = 0; i < 4; ++i)
#pragma unroll
            for (int r = 0; r < 4; ++r)
                os[(i * 16 + quad * 4 + r) * OSL + col] = acc[i][tt][r] + bv;
    }
    __syncthreads();

#pragma unroll
    for (int it = 0; it < 8; ++it) {
        int fi  = it * 256 + tid;
        int row = fi >> 5, c4 = fi & 31;
        if (m0 + row < n) {
            float4 xv = ((const float4*)x)[(size_t)(m0 + row) * 32 + c4];
            float4 av = *(const float4*)(&os[row * OSL + c4 * 4]);
            float4 ov = {xv.x + av.x, xv.y + av.y, xv.z + av.z, xv.w + av.w};
            ((float4*)out)[(size_t)(m0 + row) * 32 + c4] = ov;
        }
    }
}

extern "C" void kernel_launch(void* const* d_in, const int* in_sizes, int n_in,
                              void* d_out, int out_size, void* d_ws, size_t ws_size,
                              hipStream_t stream) {
    const float* x      = (const float*)d_in[0];
    const int*   eidx   = (const int*)d_in[1];
    const int*   eattr  = (const int*)d_in[2];
    const float* pre_w  = (const float*)d_in[3];
    const float* pre_b  = (const float*)d_in[4];
    const float* msg0_w = (const float*)d_in[5];
    const float* msg0_b = (const float*)d_in[6];
    const float* msg1_w = (const float*)d_in[7];
    const float* msg1_b = (const float*)d_in[8];
    const float* msg2_w = (const float*)d_in[9];
    const float* msg2_b = (const float*)d_in[10];
    const float* msg3_w = (const float*)d_in[11];
    const float* msg3_b = (const float*)d_in[12];
    const float* r0w    = (const float*)d_in[13];
    const float* r0b    = (const float*)d_in[14];
    const float* r1w    = (const float*)d_in[15];
    const float* r1b    = (const float*)d_in[16];
    const float* r2w    = (const float*)d_in[17];
    const float* r2b    = (const float*)d_in[18];
    const float* post_w = (const float*)d_in[19];
    const float* post_b = (const float*)d_in[20];
    const float* emb0   = (const float*)d_in[21];
    const float* emb1   = (const float*)d_in[22];
    const float* emb2   = (const float*)d_in[23];
    const float* emb3   = (const float*)d_in[24];
    const float* einit  = (const float*)d_in[25];
    const float* init0  = (const float*)d_in[26];

    int n = in_sizes[0] / WIDTH;
    int E = in_sizes[2] / 4;
    size_t NW = (size_t)n * WIDTH;

    float* ws   = (float*)d_ws;
    float* A    = ws;                              // [N,128] f32 (full path only)
    float* U    = ws + NW;                         // [3][34][128]
    float* Uc   = U + 3 * 34 * WIDTH;              // [3][NCOMBO][128]
    float* scal = Uc + 3 * (size_t)NCOMBO * WIDTH; // [2]
    short* sw   = (short*)(scal + 2);
    short* preF  = sw;                             // 6 x 16384 bf16 frag-order weights
    short* w0F   = sw + 16384;
    short* w1F   = sw + 2 * 16384;
    short* w2F   = sw + 3 * 16384;
    short* w3F   = sw + 4 * 16384;
    short* postF = sw + 5 * 16384;
    short* Bb    = sw + 6 * 16384;                 // [N,128] bf16 (full path)
    short* Cb    = Bb + NW;                        // [N,128] bf16
    short* Gb    = Cb + NW;                        // [N,128] bf16
    short* hb    = Gb + NW;                        // [N,128] bf16
    int*   ib       = (int*)(hb + NW);
    int*   offsets  = ib;                          // n+1
    int*   counts   = offsets + (n + 1);           // n   } memset zeroes
    int*   done     = counts + n;                  // 1   } these together
    int*   lscan    = done + 1;                    // n
    int*   partials = lscan + n;                   // <=1024
    int*   rank     = partials + 1024;             // E
    uint2* s_pk     = (uint2*)(rank + E);          // E (8B each)

    hipMemsetAsync(counts, 0, ((size_t)n + 1) * sizeof(int), stream);  // counts + done

    // F1: weight swizzle + U tables + hist(rank)
    int f1_total = TOTW + TOTU + E;
    k_f1<<<(f1_total + 255) / 256, 256, 0, stream>>>(
        einit, init0, emb0, emb1, emb2, emb3,
        r0w, r0b, r1w, r1b, r2w, r2b,
        pre_w, msg0_w, msg1_w, msg2_w, msg3_w, post_w,
        preF, w0F, w1F, w2F, w3F, postF, U, scal,
        eidx, counts, rank, E);

    // F2: scan1 (+inline scan2 by last finisher) + prepc
    int sb  = (n + 255) / 256;
    int pcb = (3 * NCOMBO + 1) / 2;
    k_f2<<<sb + pcb, 256, 0, stream>>>(counts, lscan, partials, done, offsets,
                                       n, sb, U, init0, Uc);

    // F3: gemm12 + scatter (inline offsets) + scan3
    int gb = (n + 63) / 64;
    int eb = (E + 255) / 256;
    k_f3<<<gb + eb + sb, 256, 0, stream>>>(
        x, preF, pre_b, w0F, msg0_b, w1F, msg1_b, w2F, msg2_b, w3F, msg3_b,
        scal, Gb, A, Bb, Cb, n,
        eidx, eattr, counts, lscan, partials, rank, offsets, s_pk, E, gb, eb);

    k_agg<<<(n + 3) / 4, 256, 0, stream>>>(offsets, s_pk, A, Bb, Cb, Uc, scal, Gb, hb, n);
    k_post<<<gb, 256, 0, stream>>>(x, hb, postF, post_b, (float*)d_out, n);
}